// Round 2
// baseline (34.952 us; speedup 1.0000x reference)
//
#include <hip/hip_runtime.h>

typedef float f32x4 __attribute__((ext_vector_type(4)));

constexpr int B_ = 8, L_ = 2048, N_ = 64;

// ---------------- Kernel A: per-row stats + attended ----------------
constexpr int ROWS_A = 16;
constexpr int THREADS_A = 256;

__global__ __launch_bounds__(THREADS_A) void attn_stats(
    const float* __restrict__ query, const float* __restrict__ key,
    const float* __restrict__ value, const float* __restrict__ Wp,
    const float* __restrict__ bp, float* __restrict__ attended,
    float* __restrict__ c1w, float* __restrict__ m2w)
{
    __shared__ f32x4 sK[L_ / 4];
    __shared__ f32x4 sV[L_ / 4];
    __shared__ float sred[8];

    const int tid  = threadIdx.x;
    const int lane = tid & 63;
    const int wave = tid >> 6;

    constexpr int BPB = L_ / ROWS_A;            // 128 blocks per batch
    const int b  = blockIdx.x / BPB;
    const int q0 = (blockIdx.x % BPB) * ROWS_A;

    const f32x4* K4 = reinterpret_cast<const f32x4*>(key + b * L_);
    const f32x4* V4 = reinterpret_cast<const f32x4*>(value + b * L_);

    float kmax = -3.4e38f, kmin = 3.4e38f;
    for (int i = tid; i < L_ / 4; i += THREADS_A) {
        f32x4 kk = K4[i];
        f32x4 vv = V4[i];
        sK[i] = kk;
        sV[i] = vv;
        kmax = fmaxf(kmax, fmaxf(fmaxf(kk.x, kk.y), fmaxf(kk.z, kk.w)));
        kmin = fminf(kmin, fminf(fminf(kk.x, kk.y), fminf(kk.z, kk.w)));
    }
    #pragma unroll
    for (int off = 32; off; off >>= 1) {
        kmax = fmaxf(kmax, __shfl_xor(kmax, off));
        kmin = fminf(kmin, __shfl_xor(kmin, off));
    }
    if (lane == 0) { sred[wave] = kmax; sred[4 + wave] = kmin; }

    const float w_l = Wp[lane];
    const float b_l = bp[lane];
    float s2 = w_l * w_l, sb = w_l * b_l;
    #pragma unroll
    for (int off = 32; off; off >>= 1) {
        s2 += __shfl_xor(s2, off);
        sb += __shfl_xor(sb, off);
    }

    __syncthreads();
    kmax = fmaxf(fmaxf(sred[0], sred[1]), fmaxf(sred[2], sred[3]));
    kmin = fminf(fminf(sred[4], sred[5]), fminf(sred[6], sred[7]));

    const float LOG2E = 1.4426950408889634f;

    for (int r = wave; r < ROWS_A; r += THREADS_A / 64) {
        const int q = q0 + r;
        const float Q     = query[b * L_ + q];
        const float alpha = fmaf(Q, s2, sb);
        const float c1    = alpha * LOG2E;
        const float m2    = (alpha > 0.f ? alpha * kmax : alpha * kmin) * LOG2E;

        float sum = 0.f, pv = 0.f;
        #pragma unroll
        for (int i = 0; i < 8; ++i) {
            f32x4 kk = sK[lane + 64 * i];
            f32x4 vv = sV[lane + 64 * i];
            float p0 = __builtin_amdgcn_exp2f(fmaf(c1, kk.x, -m2));
            float p1 = __builtin_amdgcn_exp2f(fmaf(c1, kk.y, -m2));
            float p2 = __builtin_amdgcn_exp2f(fmaf(c1, kk.z, -m2));
            float p3 = __builtin_amdgcn_exp2f(fmaf(c1, kk.w, -m2));
            sum += (p0 + p1) + (p2 + p3);
            pv  += (p0 * vv.x + p1 * vv.y) + (p2 * vv.z + p3 * vv.w);
        }
        #pragma unroll
        for (int off = 32; off; off >>= 1) {
            sum += __shfl_xor(sum, off);
            pv  += __shfl_xor(pv, off);
        }
        const float vbar = pv / sum;
        attended[(size_t)(b * L_ + q) * N_ + lane] = fmaf(vbar, w_l, b_l);

        if (lane == 0) {
            const int row = b * L_ + q;
            c1w[row] = c1;
            // fold normalization into the exponent: w = exp2(c1*K - m2')
            m2w[row] = m2 + __builtin_amdgcn_logf(sum);  // v_log_f32 = log2
        }
    }
}

// ---------------- Kernel B: pure weights store stream ----------------
constexpr int ROWS_B = 2;        // rows per wave
constexpr int THREADS_B = 256;   // 4 waves -> 8 rows per block

__global__ __launch_bounds__(THREADS_B) void attn_weights(
    const float* __restrict__ key, const float* __restrict__ c1w,
    const float* __restrict__ m2w, float* __restrict__ weights)
{
    const int tid  = threadIdx.x;
    const int lane = tid & 63;
    const int wave = tid >> 6;

    constexpr int RPB = 4 * ROWS_B;              // 8 rows per block
    constexpr int BPB = L_ / RPB;                // 256 blocks per batch
    const int b  = blockIdx.x / BPB;
    const int q0 = (blockIdx.x % BPB) * RPB + wave * ROWS_B;

    const f32x4* K4 = reinterpret_cast<const f32x4*>(key + b * L_);

    // K row lives in registers for both rows this wave handles.
    f32x4 kk[8];
    #pragma unroll
    for (int i = 0; i < 8; ++i) kk[i] = K4[lane + 64 * i];

    #pragma unroll
    for (int r = 0; r < ROWS_B; ++r) {
        const int row = b * L_ + q0 + r;
        const float c1  = c1w[row];
        const float m2p = m2w[row];
        f32x4* wrow = reinterpret_cast<f32x4*>(weights + (size_t)row * L_);
        #pragma unroll
        for (int i = 0; i < 8; ++i) {
            f32x4 o;
            o.x = __builtin_amdgcn_exp2f(fmaf(c1, kk[i].x, -m2p));
            o.y = __builtin_amdgcn_exp2f(fmaf(c1, kk[i].y, -m2p));
            o.z = __builtin_amdgcn_exp2f(fmaf(c1, kk[i].z, -m2p));
            o.w = __builtin_amdgcn_exp2f(fmaf(c1, kk[i].w, -m2p));
            wrow[lane + 64 * i] = o;
        }
    }
}

extern "C" void kernel_launch(void* const* d_in, const int* in_sizes, int n_in,
                              void* d_out, int out_size, void* d_ws, size_t ws_size,
                              hipStream_t stream) {
    const float* query = (const float*)d_in[0];
    const float* key   = (const float*)d_in[1];
    const float* value = (const float*)d_in[2];
    const float* W     = (const float*)d_in[3];
    const float* bvec  = (const float*)d_in[4];

    float* attended = (float*)d_out;                          // [B,L,N]
    float* weights  = (float*)d_out + (size_t)B_ * L_ * N_;   // [B,L,L]

    float* c1w = (float*)d_ws;                 // [B*L]
    float* m2w = (float*)d_ws + B_ * L_;       // [B*L]  (needs 128 KB ws)

    attn_stats<<<dim3(B_ * (L_ / ROWS_A)), THREADS_A, 0, stream>>>(
        query, key, value, W, bvec, attended, c1w, m2w);

    attn_weights<<<dim3(B_ * (L_ / (4 * ROWS_B))), THREADS_B, 0, stream>>>(
        key, c1w, m2w, weights);
}

// Round 3
// 26.998 us; speedup vs baseline: 1.2946x; 1.2946x over previous
//
#include <hip/hip_runtime.h>

typedef float f32x4 __attribute__((ext_vector_type(4)));

constexpr int B_ = 8, L_ = 2048, N_ = 64;
constexpr int RPW = 4;            // rows per wave
constexpr int THREADS = 256;      // 4 waves per block
constexpr int RPB = RPW * 4;      // 16 rows per block

__global__ __launch_bounds__(THREADS) void attn_all(
    const float* __restrict__ query, const float* __restrict__ key,
    const float* __restrict__ value, const float* __restrict__ Wp,
    const float* __restrict__ bp, float* __restrict__ attended,
    float* __restrict__ weights)
{
    const int tid  = threadIdx.x;
    const int lane = tid & 63;
    const int wave = tid >> 6;

    constexpr int BPB = L_ / RPB;                 // 128 blocks per batch
    const int b  = blockIdx.x / BPB;
    const int q0 = (blockIdx.x % BPB) * RPB + wave * RPW;

    const f32x4* K4 = reinterpret_cast<const f32x4*>(key + b * L_);
    const f32x4* V4 = reinterpret_cast<const f32x4*>(value + b * L_);

    // Whole K and V rows live in registers for this wave (8 KB each).
    f32x4 kk[8], vv[8];
    #pragma unroll
    for (int i = 0; i < 8; ++i) { kk[i] = K4[lane + 64 * i]; vv[i] = V4[lane + 64 * i]; }

    // s2 = sum W^2, sb = sum W*b
    const float w_l = Wp[lane];
    const float b_l = bp[lane];
    float s2 = w_l * w_l, sb = w_l * b_l;
    #pragma unroll
    for (int off = 32; off; off >>= 1) {
        s2 += __shfl_xor(s2, off);
        sb += __shfl_xor(sb, off);
    }

    // kmax/kmin over the register-resident K row
    float kmax = -3.4e38f, kmin = 3.4e38f;
    #pragma unroll
    for (int i = 0; i < 8; ++i) {
        kmax = fmaxf(kmax, fmaxf(fmaxf(kk[i].x, kk[i].y), fmaxf(kk[i].z, kk[i].w)));
        kmin = fminf(kmin, fminf(fminf(kk[i].x, kk[i].y), fminf(kk[i].z, kk[i].w)));
    }
    #pragma unroll
    for (int off = 32; off; off >>= 1) {
        kmax = fmaxf(kmax, __shfl_xor(kmax, off));
        kmin = fminf(kmin, __shfl_xor(kmin, off));
    }

    const float LOG2E = 1.4426950408889634f;

    // ---- Phase 1: per-row stats (c1, m2' with normalization folded in) ----
    float c1a[RPW], m2a[RPW];
    #pragma unroll
    for (int r = 0; r < RPW; ++r) {
        const float Q     = query[b * L_ + q0 + r];
        const float alpha = fmaf(Q, s2, sb);
        const float c1    = alpha * LOG2E;
        const float m2    = (alpha > 0.f ? alpha * kmax : alpha * kmin) * LOG2E;

        float sum = 0.f, pv = 0.f;
        #pragma unroll
        for (int i = 0; i < 8; ++i) {
            float p0 = __builtin_amdgcn_exp2f(fmaf(c1, kk[i].x, -m2));
            float p1 = __builtin_amdgcn_exp2f(fmaf(c1, kk[i].y, -m2));
            float p2 = __builtin_amdgcn_exp2f(fmaf(c1, kk[i].z, -m2));
            float p3 = __builtin_amdgcn_exp2f(fmaf(c1, kk[i].w, -m2));
            sum += (p0 + p1) + (p2 + p3);
            pv  += (p0 * vv[i].x + p1 * vv[i].y) + (p2 * vv[i].z + p3 * vv[i].w);
        }
        #pragma unroll
        for (int off = 32; off; off >>= 1) {
            sum += __shfl_xor(sum, off);
            pv  += __shfl_xor(pv, off);
        }
        const float vbar = pv / sum;
        attended[(size_t)(b * L_ + q0 + r) * N_ + lane] = fmaf(vbar, w_l, b_l);

        c1a[r] = c1;
        m2a[r] = m2 + __builtin_amdgcn_logf(sum);   // v_log_f32 = log2
    }

    // ---- Phase 2: pure store stream (fma -> exp2 -> dwordx4 store) ----
    #pragma unroll
    for (int r = 0; r < RPW; ++r) {
        const float c1  = c1a[r];
        const float m2p = m2a[r];
        f32x4* wrow = reinterpret_cast<f32x4*>(weights + (size_t)(b * L_ + q0 + r) * L_);
        #pragma unroll
        for (int i = 0; i < 8; ++i) {
            f32x4 o;
            o.x = __builtin_amdgcn_exp2f(fmaf(c1, kk[i].x, -m2p));
            o.y = __builtin_amdgcn_exp2f(fmaf(c1, kk[i].y, -m2p));
            o.z = __builtin_amdgcn_exp2f(fmaf(c1, kk[i].z, -m2p));
            o.w = __builtin_amdgcn_exp2f(fmaf(c1, kk[i].w, -m2p));
            wrow[lane + 64 * i] = o;
        }
    }
}

extern "C" void kernel_launch(void* const* d_in, const int* in_sizes, int n_in,
                              void* d_out, int out_size, void* d_ws, size_t ws_size,
                              hipStream_t stream) {
    const float* query = (const float*)d_in[0];
    const float* key   = (const float*)d_in[1];
    const float* value = (const float*)d_in[2];
    const float* W     = (const float*)d_in[3];
    const float* bvec  = (const float*)d_in[4];

    float* attended = (float*)d_out;                          // [B,L,N]
    float* weights  = (float*)d_out + (size_t)B_ * L_ * N_;   // [B,L,L]

    attn_all<<<dim3(B_ * (L_ / RPB)), THREADS, 0, stream>>>(
        query, key, value, W, bvec, attended, weights);
}

// Round 4
// 26.221 us; speedup vs baseline: 1.3330x; 1.0296x over previous
//
#include <hip/hip_runtime.h>

typedef float f32x4 __attribute__((ext_vector_type(4)));

constexpr int B_ = 8, L_ = 2048, N_ = 64;
constexpr int RPW = 2;            // rows per wave
constexpr int THREADS = 256;      // 4 waves per block
constexpr int RPB = RPW * 4;      // 8 rows per block

__global__ __launch_bounds__(THREADS) void attn_all(
    const float* __restrict__ query, const float* __restrict__ key,
    const float* __restrict__ value, const float* __restrict__ Wp,
    const float* __restrict__ bp, float* __restrict__ attended,
    float* __restrict__ weights)
{
    const int tid  = threadIdx.x;
    const int lane = tid & 63;
    const int wave = tid >> 6;

    constexpr int BPB = L_ / RPB;                 // 256 blocks per batch
    const int b  = blockIdx.x / BPB;
    const int q0 = (blockIdx.x % BPB) * RPB + wave * RPW;

    const f32x4* K4 = reinterpret_cast<const f32x4*>(key + b * L_);
    const f32x4* V4 = reinterpret_cast<const f32x4*>(value + b * L_);

    // Whole K and V rows live in registers for this wave (8 KB each).
    f32x4 kk[8], vv[8];
    #pragma unroll
    for (int i = 0; i < 8; ++i) { kk[i] = K4[lane + 64 * i]; vv[i] = V4[lane + 64 * i]; }

    // s2 = sum W^2, sb = sum W*b
    const float w_l = Wp[lane];
    const float b_l = bp[lane];
    float s2 = w_l * w_l, sb = w_l * b_l;
    #pragma unroll
    for (int off = 32; off; off >>= 1) {
        s2 += __shfl_xor(s2, off);
        sb += __shfl_xor(sb, off);
    }

    // kmax/kmin over the register-resident K row
    float kmax = -3.4e38f, kmin = 3.4e38f;
    #pragma unroll
    for (int i = 0; i < 8; ++i) {
        kmax = fmaxf(kmax, fmaxf(fmaxf(kk[i].x, kk[i].y), fmaxf(kk[i].z, kk[i].w)));
        kmin = fminf(kmin, fminf(fminf(kk[i].x, kk[i].y), fminf(kk[i].z, kk[i].w)));
    }
    #pragma unroll
    for (int off = 32; off; off >>= 1) {
        kmax = fmaxf(kmax, __shfl_xor(kmax, off));
        kmin = fminf(kmin, __shfl_xor(kmin, off));
    }

    const float LOG2E = 1.4426950408889634f;

    // Per row: exps (kept in registers) -> reduce -> scale+store immediately.
    #pragma unroll
    for (int r = 0; r < RPW; ++r) {
        const int row = b * L_ + q0 + r;
        const float Q     = query[row];
        const float alpha = fmaf(Q, s2, sb);
        const float c1    = alpha * LOG2E;
        const float m2    = (alpha > 0.f ? alpha * kmax : alpha * kmin) * LOG2E;

        float p[32];
        float sum = 0.f, pv = 0.f;
        #pragma unroll
        for (int i = 0; i < 8; ++i) {
            float p0 = __builtin_amdgcn_exp2f(fmaf(c1, kk[i].x, -m2));
            float p1 = __builtin_amdgcn_exp2f(fmaf(c1, kk[i].y, -m2));
            float p2 = __builtin_amdgcn_exp2f(fmaf(c1, kk[i].z, -m2));
            float p3 = __builtin_amdgcn_exp2f(fmaf(c1, kk[i].w, -m2));
            p[4 * i + 0] = p0; p[4 * i + 1] = p1;
            p[4 * i + 2] = p2; p[4 * i + 3] = p3;
            sum += (p0 + p1) + (p2 + p3);
            pv  += (p0 * vv[i].x + p1 * vv[i].y) + (p2 * vv[i].z + p3 * vv[i].w);
        }
        #pragma unroll
        for (int off = 32; off; off >>= 1) {
            sum += __shfl_xor(sum, off);
            pv  += __shfl_xor(pv, off);
        }
        const float inv  = __builtin_amdgcn_rcpf(sum);
        const float vbar = pv * inv;

        attended[(size_t)row * N_ + lane] = fmaf(vbar, w_l, b_l);

        f32x4* wrow = reinterpret_cast<f32x4*>(weights + (size_t)row * L_);
        #pragma unroll
        for (int i = 0; i < 8; ++i) {
            f32x4 o;
            o.x = p[4 * i + 0] * inv;
            o.y = p[4 * i + 1] * inv;
            o.z = p[4 * i + 2] * inv;
            o.w = p[4 * i + 3] * inv;
            wrow[lane + 64 * i] = o;
        }
    }
}

extern "C" void kernel_launch(void* const* d_in, const int* in_sizes, int n_in,
                              void* d_out, int out_size, void* d_ws, size_t ws_size,
                              hipStream_t stream) {
    const float* query = (const float*)d_in[0];
    const float* key   = (const float*)d_in[1];
    const float* value = (const float*)d_in[2];
    const float* W     = (const float*)d_in[3];
    const float* bvec  = (const float*)d_in[4];

    float* attended = (float*)d_out;                          // [B,L,N]
    float* weights  = (float*)d_out + (size_t)B_ * L_ * N_;   // [B,L,L]

    attn_all<<<dim3(B_ * (L_ / RPB)), THREADS, 0, stream>>>(
        query, key, value, W, bvec, attended, weights);
}